// Round 9
// baseline (26.322 us; speedup 1.0000x reference)
//
#include <hip/hip_runtime.h>
#include <hip/hip_bf16.h>

using floatx4 = __attribute__((ext_vector_type(4))) float;
using shortx8 = __attribute__((ext_vector_type(8))) short;
using uintx2  = __attribute__((ext_vector_type(2))) unsigned int;

constexpr int M = 32, N = 4096, K = 4096;
constexpr int WAVES = 8;              // waves per block
constexpr int KSPLIT = 2;             // k-slices (blocks per o-tile)
constexpr int WSPAN = K / KSPLIT / WAVES;   // 256 k per wave
constexpr int CH = 64;                // k per chunk
constexpr int NCH = WSPAN / CH;       // 4 chunks per wave

__device__ __forceinline__ unsigned int pk_bf16(float a, float b) {
    __hip_bfloat16 ha = __float2bfloat16(a), hb = __float2bfloat16(b);
    return (unsigned int)*reinterpret_cast<unsigned short*>(&ha) |
           ((unsigned int)*reinterpret_cast<unsigned short*>(&hb) << 16);
}

// ---- init: pack x into fragment-ordered bf16 AND out = bias (poison-safe).
// xfrag layout: [kblk(128)][half(2)][lane(64)][j(8)] shorts; lane L holds
// batch b = half*16 + (L&15), k = kblk*32 + (L>>4)*8 + j.
__global__ __launch_bounds__(256) void pack_init(
    const float* __restrict__ x, const float* __restrict__ bias,
    float* __restrict__ out, short* __restrict__ xfrag)
{
    int i = blockIdx.x * blockDim.x + threadIdx.x;   // 32768 threads
    if (i < M * K / 8) {
        int g = i;
        int kblk = g >> 7, rem = g & 127;
        int half = rem >> 6, lane = rem & 63;
        int b = half * 16 + (lane & 15);
        int k = kblk * 32 + (lane >> 4) * 8;
        const float* src = x + (size_t)b * K + k;
        shortx8 v;
        #pragma unroll
        for (int j = 0; j < 8; ++j) {
            __hip_bfloat16 h = __float2bfloat16(src[j]);
            v[j] = *reinterpret_cast<short*>(&h);
        }
        *reinterpret_cast<shortx8*>(xfrag + (size_t)g * 8) = v;
    }
    // out = bias (float4), M*N/4 = 32768 items
    floatx4 b4 = reinterpret_cast<const floatx4*>(bias)[i & (N / 4 - 1)];
    reinterpret_cast<floatx4*>(out)[i] = b4;
}

// ---- main GEMM: 512 blocks (16 o-rows x 2048 k each) x 512 threads (8 waves).
// Wave: 256 k in 4 chunks of 64. W: coalesced global -> reg dequant ->
// XOR-swizzled wave-private LDS -> ds_read_b128 frags. x: direct fragment
// register loads (prefetch slot sl^1, compute reads sl). In-block LDS reduce,
// then one relaxed atomicAdd per output per block (out pre-inited to bias).
__global__ __launch_bounds__(512, 4) void gemm_main(
    const float* __restrict__ W, const float* __restrict__ scales,
    const short* __restrict__ xfrag, const float* __restrict__ tscale,
    float* __restrict__ out)
{
    __shared__ __align__(16) char lds[WAVES * 2 * 2048];   // 32 KB

    const int t    = threadIdx.x;
    const int lane = t & 63;
    const int wave = t >> 6;
    const int o0   = blockIdx.x * 16;
    const int kw0  = blockIdx.y * (K / KSPLIT) + wave * WSPAN;

    const float rt = 1.0f / tscale[0];

    // W staging per chunk: 16 rows x 64 k f32 = 4KB; per lane 4x float4.
    // flat = j*64+lane: row = flat>>4 (0..15), seg = flat&15 (16B units)
    floatx4 wr[2][4]; float sc[2][4];
    shortx8 xa[2][2], xb[2][2];

    auto issueW = [&](int c, int sl) {
        const int kc = kw0 + c * CH;
        #pragma unroll
        for (int j = 0; j < 4; ++j) {
            int flat = j * 64 + lane, row = flat >> 4, seg = flat & 15;
            wr[sl][j] = *reinterpret_cast<const floatx4*>(
                W + (size_t)(o0 + row) * K + kc + seg * 4);
            sc[sl][j] = scales[(size_t)(o0 + row) * (K / 16) + (kc >> 4) + (seg >> 2)];
        }
        __builtin_amdgcn_sched_barrier(0);   // pin issue point
    };
    auto loadX = [&](int c, int sl) {
        const int kb0 = (kw0 + c * CH) >> 5;
        #pragma unroll
        for (int b = 0; b < 2; ++b) {
            xa[sl][b] = *reinterpret_cast<const shortx8*>(
                xfrag + ((size_t)(kb0 + b) * 2 + 0) * 512 + lane * 8);
            xb[sl][b] = *reinterpret_cast<const shortx8*>(
                xfrag + ((size_t)(kb0 + b) * 2 + 1) * 512 + lane * 8);
        }
        __builtin_amdgcn_sched_barrier(0);
    };

    char* mybuf = lds + wave * 4096;
    auto stage = [&](int c, int sl) {
        char* buf = mybuf + sl * 2048;
        #pragma unroll
        for (int j = 0; j < 4; ++j) {
            int flat = j * 64 + lane, row = flat >> 4, seg = flat & 15;
            float rs = rt * __builtin_amdgcn_rcpf(sc[sl][j]);
            uintx2 pv = { pk_bf16(wr[sl][j][0] * rs, wr[sl][j][1] * rs),
                          pk_bf16(wr[sl][j][2] * rs, wr[sl][j][3] * rs) };
            int slot = seg >> 1, half = seg & 1;   // 8B granule within row
            *reinterpret_cast<uintx2*>(
                buf + row * 128 + ((slot ^ row) & 7) * 16 + half * 8) = pv;
        }
    };

    floatx4 acc0 = {0.f, 0.f, 0.f, 0.f};
    floatx4 acc1 = {0.f, 0.f, 0.f, 0.f};
    const int fr = lane & 15, kg = lane >> 4;

    issueW(0, 0);
    issueW(1, 1);
    loadX(0, 0);

    #pragma unroll
    for (int c = 0; c < NCH; ++c) {
        const int sl = c & 1;
        if (c + 1 < NCH) loadX(c + 1, sl ^ 1);   // x prefetch: other slot
        stage(c, sl);                             // consumes wr[sl]
        if (c + 2 < NCH) issueW(c + 2, sl);       // refill wr[sl]
        char* buf = mybuf + sl * 2048;
        #pragma unroll
        for (int b = 0; b < 2; ++b) {             // 2 k-steps of 32
            int slot = b * 4 + kg;
            shortx8 wf = *reinterpret_cast<const shortx8*>(
                buf + fr * 128 + ((slot ^ fr) & 7) * 16);
            acc0 = __builtin_amdgcn_mfma_f32_16x16x32_bf16(xa[sl][b], wf, acc0, 0, 0, 0);
            acc1 = __builtin_amdgcn_mfma_f32_16x16x32_bf16(xb[sl][b], wf, acc1, 0, 0, 0);
        }
    }

    // ---- in-block reduce across 8 waves (reuse LDS) ----
    __syncthreads();
    float* red = (float*)lds;               // [wave][e(0..7)][lane] = 16 KB
    #pragma unroll
    for (int r = 0; r < 4; ++r) {
        red[(wave * 8 + r) * 64 + lane]     = acc0[r];
        red[(wave * 8 + 4 + r) * 64 + lane] = acc1[r];
    }
    __syncthreads();

    // t -> (b = t>>4, oc = t&15); b = hi*16 + kgq*4 + r;
    // value at red[w][hi*4+r][kgq*16+oc]
    {
        int b = t >> 4, oc = t & 15;
        int hi = b >> 4, kgq = (b >> 2) & 3, r = b & 3;
        int e = hi * 4 + r, ls = kgq * 16 + oc;
        float v = 0.f;
        #pragma unroll
        for (int w = 0; w < WAVES; ++w)
            v += red[(w * 8 + e) * 64 + ls];
        atomicAdd(out + (size_t)b * N + o0 + oc, v);   // relaxed, device scope
    }
}

// ---- fallback (tiny ws): atomic split-K, x as f32
__global__ __launch_bounds__(256) void init_bias(
    const float* __restrict__ bias, float* __restrict__ out)
{
    int i = blockIdx.x * blockDim.x + threadIdx.x;
    if (i < M * N) out[i] = bias[i & (N - 1)];
}

__global__ __launch_bounds__(256) void gemm_atomic(
    const float* __restrict__ W, const float* __restrict__ scales,
    const float* __restrict__ xf32, const float* __restrict__ tscale,
    float* __restrict__ out)
{
    const int lane = threadIdx.x & 63;
    const int wave = threadIdx.x >> 6;
    const int o0 = blockIdx.x * 64 + wave * 16;
    const int k0 = blockIdx.y * 128;
    const int row = lane & 15, kg = lane >> 4;

    const float* wp  = W + (size_t)(o0 + row) * K + k0 + kg * 8;
    const float* sp  = scales + (size_t)(o0 + row) * (K / 16) + (k0 >> 4) + (kg >> 1);
    const float* xf0 = xf32 + (size_t)row * K + k0 + kg * 8;
    const float* xf1 = xf32 + (size_t)(row + 16) * K + k0 + kg * 8;
    const float rt = 1.0f / tscale[0];

    floatx4 acc0 = {0.f, 0.f, 0.f, 0.f};
    floatx4 acc1 = {0.f, 0.f, 0.f, 0.f};
    for (int i = 0; i < 4; ++i) {
        floatx4 w0 = *reinterpret_cast<const floatx4*>(wp + i * 32);
        floatx4 w1 = *reinterpret_cast<const floatx4*>(wp + i * 32 + 4);
        float s = sp[2 * i];
        shortx8 xav, xbv, wf;
        const float rs = rt / s;
        #pragma unroll
        for (int j = 0; j < 8; ++j) {
            float a = xf0[i * 32 + j], bb = xf1[i * 32 + j];
            float wv = (j < 4 ? w0[j] : w1[j - 4]) * rs;
            __hip_bfloat16 ha = __float2bfloat16(a);
            __hip_bfloat16 hb = __float2bfloat16(bb);
            __hip_bfloat16 hw = __float2bfloat16(wv);
            xav[j] = *reinterpret_cast<short*>(&ha);
            xbv[j] = *reinterpret_cast<short*>(&hb);
            wf[j]  = *reinterpret_cast<short*>(&hw);
        }
        acc0 = __builtin_amdgcn_mfma_f32_16x16x32_bf16(xav, wf, acc0, 0, 0, 0);
        acc1 = __builtin_amdgcn_mfma_f32_16x16x32_bf16(xbv, wf, acc1, 0, 0, 0);
    }
    float* op0 = out + (size_t)(kg * 4) * N + o0 + row;
    float* op1 = out + (size_t)(16 + kg * 4) * N + o0 + row;
    #pragma unroll
    for (int r = 0; r < 4; ++r) {
        atomicAdd(op0 + (size_t)r * N, acc0[r]);
        atomicAdd(op1 + (size_t)r * N, acc1[r]);
    }
}

extern "C" void kernel_launch(void* const* d_in, const int* in_sizes, int n_in,
                              void* d_out, int out_size, void* d_ws, size_t ws_size,
                              hipStream_t stream)
{
    const float* x      = (const float*)d_in[0];
    const float* W      = (const float*)d_in[1];
    const float* tscale = (const float*)d_in[2];
    const float* scales = (const float*)d_in[3];
    const float* bias   = (const float*)d_in[4];
    float* out = (float*)d_out;

    const size_t xfrag_bytes = (size_t)M * K * sizeof(short);   // 256 KiB

    if (ws_size >= xfrag_bytes) {
        short* xfrag = (short*)d_ws;
        pack_init<<<(M * N / 4) / 256, 256, 0, stream>>>(x, bias, out, xfrag);
        dim3 grid(N / 16, KSPLIT);
        gemm_main<<<grid, 512, 0, stream>>>(W, scales, xfrag, tscale, out);
    } else {
        init_bias<<<(M * N + 255) / 256, 256, 0, stream>>>(bias, out);
        dim3 grid(N / 64, K / 128);
        gemm_atomic<<<grid, 256, 0, stream>>>(W, scales, x, tscale, out);
    }
}

// Round 10
// 25.582 us; speedup vs baseline: 1.0289x; 1.0289x over previous
//
#include <hip/hip_runtime.h>
#include <hip/hip_bf16.h>

using floatx4 = __attribute__((ext_vector_type(4))) float;
using shortx8 = __attribute__((ext_vector_type(8))) short;
using uintx2  = __attribute__((ext_vector_type(2))) unsigned int;

constexpr int M = 32, N = 4096, K = 4096;
constexpr int WAVES = 8;              // waves per block
constexpr int WSPAN = K / WAVES;      // 512 k per wave
constexpr int CH = 64;                // k per chunk
constexpr int NCH = WSPAN / CH;       // 8 chunks per wave

__device__ __forceinline__ unsigned int pk_bf16(float a, float b) {
    __hip_bfloat16 ha = __float2bfloat16(a), hb = __float2bfloat16(b);
    return (unsigned int)*reinterpret_cast<unsigned short*>(&ha) |
           ((unsigned int)*reinterpret_cast<unsigned short*>(&hb) << 16);
}

// ---- single fused GEMM: 256 blocks (16 o-rows each) x 512 threads (8 waves).
// Wave w: k in [w*512,(w+1)*512), 8 chunks of 64.
// W: coalesced global -> reg dequant -> XOR-swizzled wave-private LDS ->
//    swizzled ds_read_b128 fragments.  (proven R8 path)
// x: f32 direct from global (L2-hot broadcast), single-slot prefetch one
//    chunk ahead, converted to bf16 fragments at chunk start.
// Epilogue: 8-wave LDS reduce + bias, plain stores. No ws, no atomics.
__global__ __launch_bounds__(512, 2) void gemm_fused1(
    const float* __restrict__ x, const float* __restrict__ W,
    const float* __restrict__ scales, const float* __restrict__ tscale,
    const float* __restrict__ bias, float* __restrict__ out)
{
    __shared__ __align__(16) char lds[WAVES * 2 * 2048];   // 32 KB

    const int t    = threadIdx.x;
    const int lane = t & 63;
    const int wave = t >> 6;
    const int o0   = blockIdx.x * 16;
    const int kw0  = wave * WSPAN;

    const float rt = 1.0f / tscale[0];
    const int fr = lane & 15, kg = lane >> 4;

    // W staging per chunk: 16 rows x 64 k f32 = 4KB; per lane 4x float4.
    // flat = j*64+lane: row = flat>>4 (0..15), seg = flat&15 (16B units)
    floatx4 wr[2][4]; float sc[2][4];
    floatx4 xf[2][2][2];        // [kstep b][half h][quad q] f32 slot (chunk c+? )
    shortx8 xa[2], xb[2];       // current chunk bf16 fragments

    auto issueW = [&](int c, int sl) {
        const int kc = kw0 + c * CH;
        #pragma unroll
        for (int j = 0; j < 4; ++j) {
            int flat = j * 64 + lane, row = flat >> 4, seg = flat & 15;
            wr[sl][j] = *reinterpret_cast<const floatx4*>(
                W + (size_t)(o0 + row) * K + kc + seg * 4);
            sc[sl][j] = scales[(size_t)(o0 + row) * (K / 16) + (kc >> 4) + (seg >> 2)];
        }
        __builtin_amdgcn_sched_barrier(0);   // pin issue point
    };

    // x fragment f32 loads for chunk c into xf slot.
    // lane: batch row = h*16+fr, k = kw0 + c*64 + b*32 + kg*8 (+4 for q=1)
    auto loadXf = [&](int c) {
        const int kc = kw0 + c * CH;
        #pragma unroll
        for (int b = 0; b < 2; ++b)
            #pragma unroll
            for (int h = 0; h < 2; ++h) {
                const float* p = x + (size_t)(h * 16 + fr) * K + kc + b * 32 + kg * 8;
                xf[b][h][0] = *reinterpret_cast<const floatx4*>(p);
                xf[b][h][1] = *reinterpret_cast<const floatx4*>(p + 4);
            }
        __builtin_amdgcn_sched_barrier(0);
    };

    // convert current xf (chunk c) -> xa/xb bf16 fragments
    auto cvtX = [&]() {
        #pragma unroll
        for (int b = 0; b < 2; ++b) {
            #pragma unroll
            for (int j = 0; j < 4; ++j) {
                __hip_bfloat16 h0 = __float2bfloat16(xf[b][0][0][j]);
                __hip_bfloat16 h1 = __float2bfloat16(xf[b][0][1][j]);
                __hip_bfloat16 h2 = __float2bfloat16(xf[b][1][0][j]);
                __hip_bfloat16 h3 = __float2bfloat16(xf[b][1][1][j]);
                xa[b][j]     = *reinterpret_cast<short*>(&h0);
                xa[b][j + 4] = *reinterpret_cast<short*>(&h1);
                xb[b][j]     = *reinterpret_cast<short*>(&h2);
                xb[b][j + 4] = *reinterpret_cast<short*>(&h3);
            }
        }
    };

    char* mybuf = lds + wave * 4096;
    auto stage = [&](int c, int sl) {
        char* buf = mybuf + sl * 2048;
        #pragma unroll
        for (int j = 0; j < 4; ++j) {
            int flat = j * 64 + lane, row = flat >> 4, seg = flat & 15;
            float rs = rt * __builtin_amdgcn_rcpf(sc[sl][j]);
            uintx2 pv = { pk_bf16(wr[sl][j][0] * rs, wr[sl][j][1] * rs),
                          pk_bf16(wr[sl][j][2] * rs, wr[sl][j][3] * rs) };
            int slot = seg >> 1, half = seg & 1;   // 8B granule within row
            *reinterpret_cast<uintx2*>(
                buf + row * 128 + ((slot ^ row) & 7) * 16 + half * 8) = pv;
        }
    };

    floatx4 acc0 = {0.f, 0.f, 0.f, 0.f};
    floatx4 acc1 = {0.f, 0.f, 0.f, 0.f};

    issueW(0, 0);
    issueW(1, 1);
    loadXf(0);

    #pragma unroll
    for (int c = 0; c < NCH; ++c) {
        const int sl = c & 1;
        cvtX();                                   // consume xf (chunk c)
        if (c + 1 < NCH) loadXf(c + 1);           // refill xf (SSA-renamed)
        stage(c, sl);                             // consumes wr[sl]
        if (c + 2 < NCH) issueW(c + 2, sl);       // refill wr[sl]
        char* buf = mybuf + sl * 2048;
        #pragma unroll
        for (int b = 0; b < 2; ++b) {             // 2 k-steps of 32
            int slot = b * 4 + kg;
            shortx8 wf = *reinterpret_cast<const shortx8*>(
                buf + fr * 128 + ((slot ^ fr) & 7) * 16);
            acc0 = __builtin_amdgcn_mfma_f32_16x16x32_bf16(xa[b], wf, acc0, 0, 0, 0);
            acc1 = __builtin_amdgcn_mfma_f32_16x16x32_bf16(xb[b], wf, acc1, 0, 0, 0);
        }
    }

    // ---- in-block reduce across 8 waves (reuse LDS) ----
    __syncthreads();
    float* red = (float*)lds;               // [wave][e(0..7)][lane] = 16 KB
    #pragma unroll
    for (int r = 0; r < 4; ++r) {
        red[(wave * 8 + r) * 64 + lane]     = acc0[r];
        red[(wave * 8 + 4 + r) * 64 + lane] = acc1[r];
    }
    __syncthreads();

    // t -> (b = t>>4, oc = t&15); b = hi*16 + kgq*4 + r;
    // value at red[w][hi*4+r][kgq*16+oc]
    {
        int b = t >> 4, oc = t & 15;
        int hi = b >> 4, kgq = (b >> 2) & 3, r = b & 3;
        int e = hi * 4 + r, ls = kgq * 16 + oc;
        float v = bias[o0 + oc];
        #pragma unroll
        for (int w = 0; w < WAVES; ++w)
            v += red[(w * 8 + e) * 64 + ls];
        out[(size_t)b * N + o0 + oc] = v;
    }
}

extern "C" void kernel_launch(void* const* d_in, const int* in_sizes, int n_in,
                              void* d_out, int out_size, void* d_ws, size_t ws_size,
                              hipStream_t stream)
{
    const float* x      = (const float*)d_in[0];
    const float* W      = (const float*)d_in[1];
    const float* tscale = (const float*)d_in[2];
    const float* scales = (const float*)d_in[3];
    const float* bias   = (const float*)d_in[4];
    float* out = (float*)d_out;

    gemm_fused1<<<N / 16, 512, 0, stream>>>(x, W, scales, tscale, bias, out);
}

// Round 11
// 23.311 us; speedup vs baseline: 1.1292x; 1.0974x over previous
//
#include <hip/hip_runtime.h>
#include <hip/hip_bf16.h>

using floatx4 = __attribute__((ext_vector_type(4))) float;
using shortx8 = __attribute__((ext_vector_type(8))) short;
using uintx2  = __attribute__((ext_vector_type(2))) unsigned int;

constexpr int M = 32, N = 4096, K = 4096;
constexpr int WAVES = 8;              // waves per block
constexpr int WSPAN = K / WAVES;      // 512 k per wave
constexpr int CH = 128;               // k per chunk
constexpr int NCH = WSPAN / CH;       // 4 chunks per wave

__device__ __forceinline__ unsigned int pk_bf16(float a, float b) {
    __hip_bfloat16 ha = __float2bfloat16(a), hb = __float2bfloat16(b);
    return (unsigned int)*reinterpret_cast<unsigned short*>(&ha) |
           ((unsigned int)*reinterpret_cast<unsigned short*>(&hb) << 16);
}

// ---- init: pack x into fragment-ordered bf16.
// layout: [kblk(128)][half(2)][lane(64)][j(8)] shorts; lane L holds
// batch b = half*16 + (L&15), k = kblk*32 + (L>>4)*8 + j.
__global__ __launch_bounds__(256) void pack_x(
    const float* __restrict__ x, short* __restrict__ xfrag)
{
    int g = blockIdx.x * blockDim.x + threadIdx.x;   // 16384 threads
    int kblk = g >> 7, rem = g & 127;
    int half = rem >> 6, lane = rem & 63;
    int b = half * 16 + (lane & 15);
    int k = kblk * 32 + (lane >> 4) * 8;
    const float* src = x + (size_t)b * K + k;
    shortx8 v;
    #pragma unroll
    for (int j = 0; j < 8; ++j) {
        __hip_bfloat16 h = __float2bfloat16(src[j]);
        v[j] = *reinterpret_cast<short*>(&h);
    }
    *reinterpret_cast<shortx8*>(xfrag + (size_t)g * 8) = v;
}

// ---- main GEMM: 256 blocks (16 o-rows each) x 512 threads (8 waves).
// Wave w: k in [w*512,(w+1)*512), 4 chunks of 128. W: coalesced global ->
// reg dequant -> XOR-swizzled wave-private LDS -> swizzled ds_read_b128.
// x: fragment register loads from xfrag (prefetch slot sl^1, compute reads sl).
__global__ __launch_bounds__(512, 2) void gemm_main(
    const float* __restrict__ W, const float* __restrict__ scales,
    const short* __restrict__ xfrag, const float* __restrict__ tscale,
    const float* __restrict__ bias, float* __restrict__ out)
{
    __shared__ __align__(16) char lds[WAVES * 2 * 4096];   // 64 KB

    const int t    = threadIdx.x;
    const int lane = t & 63;
    const int wave = t >> 6;
    const int o0   = blockIdx.x * 16;
    const int kw0  = wave * WSPAN;

    const float rt = 1.0f / tscale[0];

    // W staging per chunk: 16 rows x 128 k f32 = 8KB; per lane 8x float4.
    // flat = j*64+lane: row = flat>>5 (0..15), seg = flat&31 (16B units)
    floatx4 wr[2][8]; float sc[2][8];
    shortx8 xa[2][4], xb[2][4];

    auto issueW = [&](int c, int sl) {
        const int kc = kw0 + c * CH;
        #pragma unroll
        for (int j = 0; j < 8; ++j) {
            int flat = j * 64 + lane, row = flat >> 5, seg = flat & 31;
            wr[sl][j] = *reinterpret_cast<const floatx4*>(
                W + (size_t)(o0 + row) * K + kc + seg * 4);
            sc[sl][j] = scales[(size_t)(o0 + row) * (K / 16) + (kc >> 4) + (seg >> 2)];
        }
        __builtin_amdgcn_sched_barrier(0);   // pin issue point
    };
    auto loadX = [&](int c, int sl) {
        const int kb0 = (kw0 + c * CH) >> 5;
        #pragma unroll
        for (int b = 0; b < 4; ++b) {
            xa[sl][b] = *reinterpret_cast<const shortx8*>(
                xfrag + ((size_t)(kb0 + b) * 2 + 0) * 512 + lane * 8);
            xb[sl][b] = *reinterpret_cast<const shortx8*>(
                xfrag + ((size_t)(kb0 + b) * 2 + 1) * 512 + lane * 8);
        }
        __builtin_amdgcn_sched_barrier(0);
    };

    char* mybuf = lds + wave * 8192;
    auto stage = [&](int c, int sl) {
        char* buf = mybuf + sl * 4096;
        #pragma unroll
        for (int j = 0; j < 8; ++j) {
            int flat = j * 64 + lane, row = flat >> 5, seg = flat & 31;
            float rs = rt * __builtin_amdgcn_rcpf(sc[sl][j]);
            uintx2 pv = { pk_bf16(wr[sl][j][0] * rs, wr[sl][j][1] * rs),
                          pk_bf16(wr[sl][j][2] * rs, wr[sl][j][3] * rs) };
            int slot = seg >> 1, half = seg & 1;   // 16B granule, 8B half
            *reinterpret_cast<uintx2*>(
                buf + row * 256 + ((slot ^ row) & 15) * 16 + half * 8) = pv;
        }
    };

    floatx4 acc0 = {0.f, 0.f, 0.f, 0.f};
    floatx4 acc1 = {0.f, 0.f, 0.f, 0.f};
    const int fr = lane & 15, kg = lane >> 4;

    issueW(0, 0);
    issueW(1, 1);
    loadX(0, 0);

    #pragma unroll
    for (int c = 0; c < NCH; ++c) {
        const int sl = c & 1;
        if (c + 1 < NCH) loadX(c + 1, sl ^ 1);   // x prefetch: other slot
        stage(c, sl);                             // consumes wr[sl]
        if (c + 2 < NCH) issueW(c + 2, sl);       // refill wr[sl] after use
        char* buf = mybuf + sl * 4096;
        #pragma unroll
        for (int b = 0; b < 4; ++b) {             // 4 k-steps of 32
            int slot = b * 4 + kg;
            shortx8 wf = *reinterpret_cast<const shortx8*>(
                buf + fr * 256 + ((slot ^ fr) & 15) * 16);
            acc0 = __builtin_amdgcn_mfma_f32_16x16x32_bf16(xa[sl][b], wf, acc0, 0, 0, 0);
            acc1 = __builtin_amdgcn_mfma_f32_16x16x32_bf16(xb[sl][b], wf, acc1, 0, 0, 0);
        }
    }

    // ---- in-block reduce across 8 waves (reuse LDS) ----
    __syncthreads();
    float* red = (float*)lds;               // [wave][e(0..7)][lane] = 16 KB
    #pragma unroll
    for (int r = 0; r < 4; ++r) {
        red[(wave * 8 + r) * 64 + lane]     = acc0[r];
        red[(wave * 8 + 4 + r) * 64 + lane] = acc1[r];
    }
    __syncthreads();

    // t -> (b = t>>4, oc = t&15); b = hi*16 + kgq*4 + r;
    // value at red[w][hi*4+r][kgq*16+oc]
    {
        int b = t >> 4, oc = t & 15;
        int hi = b >> 4, kgq = (b >> 2) & 3, r = b & 3;
        int e = hi * 4 + r, ls = kgq * 16 + oc;
        float v = bias[o0 + oc];
        #pragma unroll
        for (int w = 0; w < WAVES; ++w)
            v += red[(w * 8 + e) * 64 + ls];
        out[(size_t)b * N + o0 + oc] = v;
    }
}

// ---- fallback (tiny ws): atomic split-K, x as f32
__global__ __launch_bounds__(256) void init_bias(
    const float* __restrict__ bias, float* __restrict__ out)
{
    int i = blockIdx.x * blockDim.x + threadIdx.x;
    if (i < M * N) out[i] = bias[i & (N - 1)];
}

__global__ __launch_bounds__(256) void gemm_atomic(
    const float* __restrict__ W, const float* __restrict__ scales,
    const float* __restrict__ xf32, const float* __restrict__ tscale,
    float* __restrict__ out)
{
    const int lane = threadIdx.x & 63;
    const int wave = threadIdx.x >> 6;
    const int o0 = blockIdx.x * 64 + wave * 16;
    const int k0 = blockIdx.y * 128;
    const int row = lane & 15, kg = lane >> 4;

    const float* wp  = W + (size_t)(o0 + row) * K + k0 + kg * 8;
    const float* sp  = scales + (size_t)(o0 + row) * (K / 16) + (k0 >> 4) + (kg >> 1);
    const float* xf0 = xf32 + (size_t)row * K + k0 + kg * 8;
    const float* xf1 = xf32 + (size_t)(row + 16) * K + k0 + kg * 8;
    const float rt = 1.0f / tscale[0];

    floatx4 acc0 = {0.f, 0.f, 0.f, 0.f};
    floatx4 acc1 = {0.f, 0.f, 0.f, 0.f};
    for (int i = 0; i < 4; ++i) {
        floatx4 w0 = *reinterpret_cast<const floatx4*>(wp + i * 32);
        floatx4 w1 = *reinterpret_cast<const floatx4*>(wp + i * 32 + 4);
        float s = sp[2 * i];
        shortx8 xav, xbv, wf;
        const float rs = rt / s;
        #pragma unroll
        for (int j = 0; j < 8; ++j) {
            float a = xf0[i * 32 + j], bb = xf1[i * 32 + j];
            float wv = (j < 4 ? w0[j] : w1[j - 4]) * rs;
            __hip_bfloat16 ha = __float2bfloat16(a);
            __hip_bfloat16 hb = __float2bfloat16(bb);
            __hip_bfloat16 hw = __float2bfloat16(wv);
            xav[j] = *reinterpret_cast<short*>(&ha);
            xbv[j] = *reinterpret_cast<short*>(&hb);
            wf[j]  = *reinterpret_cast<short*>(&hw);
        }
        acc0 = __builtin_amdgcn_mfma_f32_16x16x32_bf16(xav, wf, acc0, 0, 0, 0);
        acc1 = __builtin_amdgcn_mfma_f32_16x16x32_bf16(xbv, wf, acc1, 0, 0, 0);
    }
    float* op0 = out + (size_t)(kg * 4) * N + o0 + row;
    float* op1 = out + (size_t)(16 + kg * 4) * N + o0 + row;
    #pragma unroll
    for (int r = 0; r < 4; ++r) {
        atomicAdd(op0 + (size_t)r * N, acc0[r]);
        atomicAdd(op1 + (size_t)r * N, acc1[r]);
    }
}

extern "C" void kernel_launch(void* const* d_in, const int* in_sizes, int n_in,
                              void* d_out, int out_size, void* d_ws, size_t ws_size,
                              hipStream_t stream)
{
    const float* x      = (const float*)d_in[0];
    const float* W      = (const float*)d_in[1];
    const float* tscale = (const float*)d_in[2];
    const float* scales = (const float*)d_in[3];
    const float* bias   = (const float*)d_in[4];
    float* out = (float*)d_out;

    const size_t xfrag_bytes = (size_t)M * K * sizeof(short);   // 256 KiB

    if (ws_size >= xfrag_bytes) {
        short* xfrag = (short*)d_ws;
        pack_x<<<(M * K / 8 + 255) / 256, 256, 0, stream>>>(x, xfrag);
        gemm_main<<<N / 16, 512, 0, stream>>>(W, scales, xfrag, tscale, bias, out);
    } else {
        init_bias<<<(M * N + 255) / 256, 256, 0, stream>>>(bias, out);
        dim3 grid(N / 64, K / 128);
        gemm_atomic<<<grid, 256, 0, stream>>>(W, scales, x, tscale, out);
    }
}

// Round 12
// 21.908 us; speedup vs baseline: 1.2015x; 1.0640x over previous
//
#include <hip/hip_runtime.h>
#include <hip/hip_bf16.h>

using floatx4 = __attribute__((ext_vector_type(4))) float;
using shortx8 = __attribute__((ext_vector_type(8))) short;
using uintx2  = __attribute__((ext_vector_type(2))) unsigned int;

constexpr int M = 32, N = 4096, K = 4096;
constexpr int WAVES = 8;              // waves per block
constexpr int WSPAN = K / WAVES;      // 512 k per wave
constexpr int CH = 64;                // k per chunk
constexpr int NCH = WSPAN / CH;       // 8 chunks per wave

__device__ __forceinline__ unsigned int pk_bf16(float a, float b) {
    __hip_bfloat16 ha = __float2bfloat16(a), hb = __float2bfloat16(b);
    return (unsigned int)*reinterpret_cast<unsigned short*>(&ha) |
           ((unsigned int)*reinterpret_cast<unsigned short*>(&hb) << 16);
}

// ---- init: pack x into fragment-ordered bf16.
// layout: [kblk(128)][half(2)][lane(64)][j(8)] shorts; lane L holds
// batch b = half*16 + (L&15), k = kblk*32 + (L>>4)*8 + j.
__global__ __launch_bounds__(256) void pack_x(
    const float* __restrict__ x, short* __restrict__ xfrag)
{
    int g = blockIdx.x * blockDim.x + threadIdx.x;   // 16384 threads
    int kblk = g >> 7, rem = g & 127;
    int half = rem >> 6, lane = rem & 63;
    int b = half * 16 + (lane & 15);
    int k = kblk * 32 + (lane >> 4) * 8;
    const float* src = x + (size_t)b * K + k;
    shortx8 v;
    #pragma unroll
    for (int j = 0; j < 8; ++j) {
        __hip_bfloat16 h = __float2bfloat16(src[j]);
        v[j] = *reinterpret_cast<short*>(&h);
    }
    *reinterpret_cast<shortx8*>(xfrag + (size_t)g * 8) = v;
}

// ---- main GEMM: 256 blocks (16 o-rows each) x 512 threads (8 waves).
// R8 structure, plus per-block chunk-index ROTATION: logical chunk c maps to
// physical cm = (c + blockIdx.x) & 7 for all global addresses. This staggers
// the k-offset phase across blocks so concurrent reads cover all DRAM
// channel granules instead of camping on the same 256B window chip-wide.
// (k-order of accumulation is irrelevant to the sum.)
__global__ __launch_bounds__(512, 4) void gemm_main(
    const float* __restrict__ W, const float* __restrict__ scales,
    const short* __restrict__ xfrag, const float* __restrict__ tscale,
    const float* __restrict__ bias, float* __restrict__ out)
{
    __shared__ __align__(16) char lds[WAVES * 2 * 2048];   // 32 KB

    const int t    = threadIdx.x;
    const int lane = t & 63;
    const int wave = t >> 6;
    const int o0   = blockIdx.x * 16;
    const int kw0  = wave * WSPAN;
    const int rot  = blockIdx.x & (NCH - 1);

    const float rt = 1.0f / tscale[0];

    // W staging per chunk: 16 rows x 64 k f32 = 4KB; per lane 4x float4.
    // flat = j*64+lane: row = flat>>4 (0..15), seg = flat&15 (16B units)
    floatx4 wr[2][4]; float sc[2][4];
    shortx8 xa[2][2], xb[2][2];

    auto issueW = [&](int c, int sl) {
        const int cm = (c + rot) & (NCH - 1);
        const int kc = kw0 + cm * CH;
        #pragma unroll
        for (int j = 0; j < 4; ++j) {
            int flat = j * 64 + lane, row = flat >> 4, seg = flat & 15;
            wr[sl][j] = *reinterpret_cast<const floatx4*>(
                W + (size_t)(o0 + row) * K + kc + seg * 4);
            sc[sl][j] = scales[(size_t)(o0 + row) * (K / 16) + (kc >> 4) + (seg >> 2)];
        }
        __builtin_amdgcn_sched_barrier(0);   // pin issue point
    };
    auto loadX = [&](int c, int sl) {
        const int cm = (c + rot) & (NCH - 1);
        const int kb0 = (kw0 + cm * CH) >> 5;
        #pragma unroll
        for (int b = 0; b < 2; ++b) {
            xa[sl][b] = *reinterpret_cast<const shortx8*>(
                xfrag + ((size_t)(kb0 + b) * 2 + 0) * 512 + lane * 8);
            xb[sl][b] = *reinterpret_cast<const shortx8*>(
                xfrag + ((size_t)(kb0 + b) * 2 + 1) * 512 + lane * 8);
        }
        __builtin_amdgcn_sched_barrier(0);
    };

    char* mybuf = lds + wave * 4096;
    auto stage = [&](int c, int sl) {
        char* buf = mybuf + sl * 2048;
        #pragma unroll
        for (int j = 0; j < 4; ++j) {
            int flat = j * 64 + lane, row = flat >> 4, seg = flat & 15;
            float rs = rt * __builtin_amdgcn_rcpf(sc[sl][j]);
            uintx2 pv = { pk_bf16(wr[sl][j][0] * rs, wr[sl][j][1] * rs),
                          pk_bf16(wr[sl][j][2] * rs, wr[sl][j][3] * rs) };
            int slot = seg >> 1, half = seg & 1;   // 8B granule within row
            *reinterpret_cast<uintx2*>(
                buf + row * 128 + ((slot ^ row) & 7) * 16 + half * 8) = pv;
        }
    };

    floatx4 acc0 = {0.f, 0.f, 0.f, 0.f};
    floatx4 acc1 = {0.f, 0.f, 0.f, 0.f};
    const int fr = lane & 15, kg = lane >> 4;

    issueW(0, 0);
    issueW(1, 1);
    loadX(0, 0);

    #pragma unroll
    for (int c = 0; c < NCH; ++c) {
        const int sl = c & 1;
        if (c + 1 < NCH) loadX(c + 1, sl ^ 1);   // x prefetch: other slot
        stage(c, sl);                             // consumes wr[sl]
        if (c + 2 < NCH) issueW(c + 2, sl);       // refill wr[sl] after use
        char* buf = mybuf + sl * 2048;
        #pragma unroll
        for (int b = 0; b < 2; ++b) {             // 2 k-steps of 32
            int slot = b * 4 + kg;
            shortx8 wf = *reinterpret_cast<const shortx8*>(
                buf + fr * 128 + ((slot ^ fr) & 7) * 16);
            acc0 = __builtin_amdgcn_mfma_f32_16x16x32_bf16(xa[sl][b], wf, acc0, 0, 0, 0);
            acc1 = __builtin_amdgcn_mfma_f32_16x16x32_bf16(xb[sl][b], wf, acc1, 0, 0, 0);
        }
    }

    // ---- in-block reduce across 8 waves (reuse LDS) ----
    __syncthreads();
    float* red = (float*)lds;               // [wave][e(0..7)][lane] = 16 KB
    #pragma unroll
    for (int r = 0; r < 4; ++r) {
        red[(wave * 8 + r) * 64 + lane]     = acc0[r];
        red[(wave * 8 + 4 + r) * 64 + lane] = acc1[r];
    }
    __syncthreads();

    // t -> (b = t>>4, oc = t&15); b = hi*16 + kgq*4 + r;
    // value at red[w][hi*4+r][kgq*16+oc]
    {
        int b = t >> 4, oc = t & 15;
        int hi = b >> 4, kgq = (b >> 2) & 3, r = b & 3;
        int e = hi * 4 + r, ls = kgq * 16 + oc;
        float v = bias[o0 + oc];
        #pragma unroll
        for (int w = 0; w < WAVES; ++w)
            v += red[(w * 8 + e) * 64 + ls];
        out[(size_t)b * N + o0 + oc] = v;
    }
}

// ---- fallback (tiny ws): atomic split-K, x as f32
__global__ __launch_bounds__(256) void init_bias(
    const float* __restrict__ bias, float* __restrict__ out)
{
    int i = blockIdx.x * blockDim.x + threadIdx.x;
    if (i < M * N) out[i] = bias[i & (N - 1)];
}

__global__ __launch_bounds__(256) void gemm_atomic(
    const float* __restrict__ W, const float* __restrict__ scales,
    const float* __restrict__ xf32, const float* __restrict__ tscale,
    float* __restrict__ out)
{
    const int lane = threadIdx.x & 63;
    const int wave = threadIdx.x >> 6;
    const int o0 = blockIdx.x * 64 + wave * 16;
    const int k0 = blockIdx.y * 128;
    const int row = lane & 15, kg = lane >> 4;

    const float* wp  = W + (size_t)(o0 + row) * K + k0 + kg * 8;
    const float* sp  = scales + (size_t)(o0 + row) * (K / 16) + (k0 >> 4) + (kg >> 1);
    const float* xf0 = xf32 + (size_t)row * K + k0 + kg * 8;
    const float* xf1 = xf32 + (size_t)(row + 16) * K + k0 + kg * 8;
    const float rt = 1.0f / tscale[0];

    floatx4 acc0 = {0.f, 0.f, 0.f, 0.f};
    floatx4 acc1 = {0.f, 0.f, 0.f, 0.f};
    for (int i = 0; i < 4; ++i) {
        floatx4 w0 = *reinterpret_cast<const floatx4*>(wp + i * 32);
        floatx4 w1 = *reinterpret_cast<const floatx4*>(wp + i * 32 + 4);
        float s = sp[2 * i];
        shortx8 xav, xbv, wf;
        const float rs = rt / s;
        #pragma unroll
        for (int j = 0; j < 8; ++j) {
            float a = xf0[i * 32 + j], bb = xf1[i * 32 + j];
            float wv = (j < 4 ? w0[j] : w1[j - 4]) * rs;
            __hip_bfloat16 ha = __float2bfloat16(a);
            __hip_bfloat16 hb = __float2bfloat16(bb);
            __hip_bfloat16 hw = __float2bfloat16(wv);
            xav[j] = *reinterpret_cast<short*>(&ha);
            xbv[j] = *reinterpret_cast<short*>(&hb);
            wf[j]  = *reinterpret_cast<short*>(&hw);
        }
        acc0 = __builtin_amdgcn_mfma_f32_16x16x32_bf16(xav, wf, acc0, 0, 0, 0);
        acc1 = __builtin_amdgcn_mfma_f32_16x16x32_bf16(xbv, wf, acc1, 0, 0, 0);
    }
    float* op0 = out + (size_t)(kg * 4) * N + o0 + row;
    float* op1 = out + (size_t)(16 + kg * 4) * N + o0 + row;
    #pragma unroll
    for (int r = 0; r < 4; ++r) {
        atomicAdd(op0 + (size_t)r * N, acc0[r]);
        atomicAdd(op1 + (size_t)r * N, acc1[r]);
    }
}

extern "C" void kernel_launch(void* const* d_in, const int* in_sizes, int n_in,
                              void* d_out, int out_size, void* d_ws, size_t ws_size,
                              hipStream_t stream)
{
    const float* x      = (const float*)d_in[0];
    const float* W      = (const float*)d_in[1];
    const float* tscale = (const float*)d_in[2];
    const float* scales = (const float*)d_in[3];
    const float* bias   = (const float*)d_in[4];
    float* out = (float*)d_out;

    const size_t xfrag_bytes = (size_t)M * K * sizeof(short);   // 256 KiB

    if (ws_size >= xfrag_bytes) {
        short* xfrag = (short*)d_ws;
        pack_x<<<(M * K / 8 + 255) / 256, 256, 0, stream>>>(x, xfrag);
        gemm_main<<<N / 16, 512, 0, stream>>>(W, scales, xfrag, tscale, bias, out);
    } else {
        init_bias<<<(M * N + 255) / 256, 256, 0, stream>>>(bias, out);
        dim3 grid(N / 64, K / 128);
        gemm_atomic<<<grid, 256, 0, stream>>>(W, scales, x, tscale, out);
    }
}